// Round 1
// baseline (108.513 us; speedup 1.0000x reference)
//
#include <hip/hip_runtime.h>
#include <stdint.h>

#define HH 2048
#define WW 2048
#define TILE 64
#define HALO 3
#define IN_DIM (TILE + 2 * HALO)   // 70

// Monotone map: float bits -> uint32 such that uint order == float order.
__device__ __forceinline__ uint32_t map_f32(uint32_t b) {
    uint32_t mask = ((int32_t)b >> 31) | 0x80000000u;  // neg: all ones, pos: 0x80000000
    return b ^ mask;
}

__device__ __forceinline__ float unmap_f32(uint32_t u) {
    uint32_t mask = (u & 0x80000000u) ? 0x80000000u : 0xFFFFFFFFu;
    uint32_t b = u ^ mask;
    return __uint_as_float(b);
}

__global__ void init_kernel(uint32_t* hist, uint32_t* state, uint32_t k) {
    int i = blockIdx.x * blockDim.x + threadIdx.x;
    if (i < 4096) hist[i] = 0;
    if (i == 0) { state[0] = 0u; state[1] = k; }
}

// Histogram of ((u >> shift) & (bins-1)) over elements with (u & mask) == prefix.
__global__ void hist_kernel(const uint4* __restrict__ in, int nvec,
                            uint32_t* __restrict__ ghist,
                            const uint32_t* __restrict__ state,
                            uint32_t mask, int shift, int bins) {
    __shared__ uint32_t lh[4096];
    for (int i = threadIdx.x; i < bins; i += blockDim.x) lh[i] = 0;
    uint32_t prefix = state[0];
    __syncthreads();
    int stride = gridDim.x * blockDim.x;
    uint32_t bm = (uint32_t)(bins - 1);
    for (int i = blockIdx.x * blockDim.x + threadIdx.x; i < nvec; i += stride) {
        uint4 v = in[i];
        uint32_t u0 = map_f32(v.x);
        uint32_t u1 = map_f32(v.y);
        uint32_t u2 = map_f32(v.z);
        uint32_t u3 = map_f32(v.w);
        if ((u0 & mask) == prefix) atomicAdd(&lh[(u0 >> shift) & bm], 1u);
        if ((u1 & mask) == prefix) atomicAdd(&lh[(u1 >> shift) & bm], 1u);
        if ((u2 & mask) == prefix) atomicAdd(&lh[(u2 >> shift) & bm], 1u);
        if ((u3 & mask) == prefix) atomicAdd(&lh[(u3 >> shift) & bm], 1u);
    }
    __syncthreads();
    for (int i = threadIdx.x; i < bins; i += blockDim.x)
        if (lh[i]) atomicAdd(&ghist[i], lh[i]);
}

// Single block, 256 threads. Finds bucket containing the k-th element,
// updates state {prefix, k_remaining}, and zeroes the histogram for reuse.
__global__ void select_kernel(uint32_t* __restrict__ hist,
                              uint32_t* __restrict__ state,
                              int shift, int bins) {
    __shared__ uint32_t sums[256];
    int tid = threadIdx.x;
    int per = bins >> 8;  // 16 or 1
    uint32_t prefix = state[0];
    uint32_t k = state[1];
    uint32_t local[16];
    uint32_t s = 0;
    for (int i = 0; i < per; ++i) {
        local[i] = hist[tid * per + i];
        s += local[i];
    }
    sums[tid] = s;
    __syncthreads();
    uint32_t excl = 0;
    for (int i = 0; i < tid; ++i) excl += sums[i];
    if (k >= excl && k < excl + s) {
        uint32_t cum = excl;
        for (int i = 0; i < per; ++i) {
            if (k < cum + local[i]) {
                state[0] = prefix | ((uint32_t)(tid * per + i) << shift);
                state[1] = k - cum;
                break;
            }
            cum += local[i];
        }
    }
    // zero own bins for the next pass
    for (int i = 0; i < per; ++i) hist[tid * per + i] = 0;
}

// Fused threshold + 7x7 maxpool (separable) + compare + write.
__global__ void nms_kernel(const float* __restrict__ x, float* __restrict__ out,
                           const uint32_t* __restrict__ state) {
    __shared__ float t_lds[IN_DIM][IN_DIM + 2];  // 70 x 72
    __shared__ float h_lds[IN_DIM][TILE];        // 70 x 64
    float med = unmap_f32(state[0]);

    int plane = blockIdx.z;
    int tr0 = blockIdx.y * TILE;
    int tc0 = blockIdx.x * TILE;
    const float* px = x + (size_t)plane * HH * WW;
    float* pout = out + (size_t)plane * HH * WW;

    // Load thresholded tile with -inf halo
    for (int i = threadIdx.x; i < IN_DIM * IN_DIM; i += blockDim.x) {
        int r = i / IN_DIM, c = i % IN_DIM;
        int gr = tr0 + r - HALO, gc = tc0 + c - HALO;
        float v = -INFINITY;
        if (gr >= 0 && gr < HH && gc >= 0 && gc < WW) {
            float xv = px[(size_t)gr * WW + gc];
            v = (xv < med) ? 0.0f : xv;
        }
        t_lds[r][c] = v;
    }
    __syncthreads();

    // Horizontal 7-max: 70 rows x 64 cols
    for (int i = threadIdx.x; i < IN_DIM * TILE; i += blockDim.x) {
        int r = i >> 6, c = i & 63;
        float m = t_lds[r][c];
        #pragma unroll
        for (int j = 1; j < 7; ++j) m = fmaxf(m, t_lds[r][c + j]);
        h_lds[r][c] = m;
    }
    __syncthreads();

    // Vertical 7-max + compare + write: 64 x 64
    for (int i = threadIdx.x; i < TILE * TILE; i += blockDim.x) {
        int r = i >> 6, c = i & 63;
        float m = h_lds[r][c];
        #pragma unroll
        for (int j = 1; j < 7; ++j) m = fmaxf(m, h_lds[r + j][c]);
        int gr = tr0 + r, gc = tc0 + c;
        float xv = px[(size_t)gr * WW + gc];
        pout[(size_t)gr * WW + gc] = (m == xv) ? xv : 0.0f;
    }
}

extern "C" void kernel_launch(void* const* d_in, const int* in_sizes, int n_in,
                              void* d_out, int out_size, void* d_ws, size_t ws_size,
                              hipStream_t stream) {
    const float* x = (const float*)d_in[0];
    float* out = (float*)d_out;
    int n = in_sizes[0];                    // 8388608
    uint32_t* hist = (uint32_t*)d_ws;       // 4096 u32
    uint32_t* state = hist + 4096;          // {prefix, k}
    uint32_t k = (uint32_t)((n - 1) / 2);
    int nvec = n / 4;

    init_kernel<<<16, 256, 0, stream>>>(hist, state, k);

    // Level 0: top 12 bits
    hist_kernel<<<2048, 256, 0, stream>>>((const uint4*)x, nvec, hist, state,
                                          0x00000000u, 20, 4096);
    select_kernel<<<1, 256, 0, stream>>>(hist, state, 20, 4096);

    // Level 1: bits [8,20)
    hist_kernel<<<2048, 256, 0, stream>>>((const uint4*)x, nvec, hist, state,
                                          0xFFF00000u, 8, 4096);
    select_kernel<<<1, 256, 0, stream>>>(hist, state, 8, 4096);

    // Level 2: bits [0,8)
    hist_kernel<<<2048, 256, 0, stream>>>((const uint4*)x, nvec, hist, state,
                                          0xFFFFFF00u, 0, 256);
    select_kernel<<<1, 256, 0, stream>>>(hist, state, 0, 256);

    // Fused threshold + 7x7 maxpool + compare
    int nplanes = n / (HH * WW);            // 2
    dim3 grid(WW / TILE, HH / TILE, nplanes);
    nms_kernel<<<grid, 256, 0, stream>>>(x, out, state);
}